// Round 1
// baseline (1690.374 us; speedup 1.0000x reference)
//
#include <hip/hip_runtime.h>
#include <math.h>

#define HW 512
#define NPIX (HW*HW)            // 262144
#define NB 4
#define NCIN 55
#define OUTX_SIZE (NB*55*NPIX)  // 57671680

// ws layout (float offsets)
#define WT_OFF 0         // 33000 floats: [3][25][55][8]
#define WSUM_OFF 33000   // 18
#define BTSUM_OFF 33018  // 1
#define S_OFF 33024      // 1200: [600][2]
#define TM_OFF 34224     // 600
#define SBM_OFF 34824    // 600

#define TILE 32
#define HALO 6
#define LH 44
#define LW 45
#define CCH 5

__global__ __launch_bounds__(1024) void prep_kernel(
    const float* __restrict__ w1, const float* __restrict__ w2, const float* __restrict__ w3,
    const float* __restrict__ wt, const float* __restrict__ bt,
    float* __restrict__ ws)
{
  const int t = threadIdx.x;
  for (int e = t; e < 33000; e += 1024) {
    int oc = e & 7;
    int rem = e >> 3;              // (d*25+tap)*55 + cin
    int cin = rem % 55;
    int dt = rem / 55;
    int d = dt / 25, tap = dt - d * 25;
    const float* wsrc = (d == 0) ? w1 : (d == 1) ? w2 : w3;
    ws[WT_OFF + e] = (oc < 6) ? wsrc[(oc * 55 + cin) * 25 + tap] : 0.f;
  }
  if (t < 18) {
    float s = 0.f;
    for (int o = 0; o < 36; o++) s += wt[o * 18 + t];
    ws[WSUM_OFF + t] = s;
  }
  if (t == 18) {
    float s = 0.f;
    for (int o = 0; o < 36; o++) s += bt[o];
    ws[BTSUM_OFF] = s;
  }
  for (int e = t; e < 1200; e += 1024) ws[S_OFF + e] = 0.f;
}

__global__ __launch_bounds__(256) void conv_kernel(
    const float* __restrict__ x, const float* __restrict__ wT,
    const float* __restrict__ bias1, const float* __restrict__ bias2,
    const float* __restrict__ bias3, float* __restrict__ out)
{
  __shared__ float xs[CCH * LH * LW];
  const int tid = threadIdx.x;
  const int h0 = blockIdx.y * TILE, w0 = blockIdx.x * TILE;
  const int bz = blockIdx.z;
  const int r = tid >> 3;          // 0..31
  const int cg = (tid & 7) * 4;    // 0,4,..,28

  float acc[18][4];
#pragma unroll
  for (int k = 0; k < 18; k++)
#pragma unroll
    for (int p = 0; p < 4; p++) acc[k][p] = 0.f;

#pragma unroll 1
  for (int c0 = 0; c0 < NCIN; c0 += CCH) {
    __syncthreads();
#pragma unroll 1
    for (int c = 0; c < CCH; c++) {
      const float* xp = x + ((size_t)(bz * NCIN + c0 + c) << 18);
      float* dst = &xs[c * (LH * LW)];
      for (int e = tid; e < LH * LH; e += 256) {
        int ih = e / LH, iw = e - ih * LH;
        int gh = h0 - HALO + ih, gw = w0 - HALO + iw;
        float v = 0.f;
        if ((unsigned)gh < (unsigned)HW && (unsigned)gw < (unsigned)HW)
          v = xp[gh * HW + gw];
        dst[ih * LW + iw] = v;
      }
    }
    __syncthreads();
#pragma unroll 1
    for (int c = 0; c < CCH; c++) {
      const int cin = c0 + c;
      const float* xl = &xs[c * (LH * LW) + (r + HALO) * LW + (cg + HALO)];
      const float* wp = wT + cin * 8;
#pragma unroll
      for (int d = 0; d < 3; d++) {
        const int dil = d + 1;
#pragma unroll
        for (int t = 0; t < 25; t++) {
          const int oh = (t / 5 - 2) * dil, ow = (t % 5 - 2) * dil;
          const float* wq = wp + (d * 25 + t) * 440;
          float xv0 = xl[oh * LW + ow + 0];
          float xv1 = xl[oh * LW + ow + 1];
          float xv2 = xl[oh * LW + ow + 2];
          float xv3 = xl[oh * LW + ow + 3];
#pragma unroll
          for (int oc = 0; oc < 6; oc++) {
            float wv = wq[oc];
            acc[d * 6 + oc][0] = fmaf(wv, xv0, acc[d * 6 + oc][0]);
            acc[d * 6 + oc][1] = fmaf(wv, xv1, acc[d * 6 + oc][1]);
            acc[d * 6 + oc][2] = fmaf(wv, xv2, acc[d * 6 + oc][2]);
            acc[d * 6 + oc][3] = fmaf(wv, xv3, acc[d * 6 + oc][3]);
          }
        }
      }
    }
  }

  const int h = h0 + r, w = w0 + cg;
  const size_t pix = (size_t)h * HW + w;
#pragma unroll
  for (int d = 0; d < 3; d++) {
    const float* bp = (d == 0) ? bias1 : (d == 1) ? bias2 : bias3;
#pragma unroll
    for (int oc = 0; oc < 6; oc++) {
      float bv = bp[oc];
      float4 v;
      v.x = fmaxf(acc[d * 6 + oc][0] + bv, 0.f);
      v.y = fmaxf(acc[d * 6 + oc][1] + bv, 0.f);
      v.z = fmaxf(acc[d * 6 + oc][2] + bv, 0.f);
      v.w = fmaxf(acc[d * 6 + oc][3] + bv, 0.f);
      *(float4*)(out + (((size_t)(bz * 55 + 36 + d * 6 + oc)) << 18) + pix) = v;
    }
  }
}

__global__ __launch_bounds__(256) void cellsum_kernel(
    const float* __restrict__ out, const int* __restrict__ row_seg,
    const int* __restrict__ col_seg, const float* __restrict__ wsum,
    const float* __restrict__ wb, float* __restrict__ S)
{
  __shared__ float part[40];
  const int tid = threadIdx.x;
  const int h = blockIdx.y;
  const int w = blockIdx.x * 256 + tid;
  if (tid < 40) part[tid] = 0.f;
  __syncthreads();
  float st = 0.f, sb = 0.f;
  const size_t pix = (size_t)h * HW + w;
#pragma unroll
  for (int b = 0; b < NB; b++)
#pragma unroll
    for (int k = 0; k < 18; k++) {
      float v = out[(((size_t)(b * 55 + 36 + k)) << 18) + pix];
      st = fmaf(wsum[k], v, st);
      sb = fmaf(wb[k], v, sb);
    }
  int cs = col_seg[w];
  atomicAdd(&part[cs * 2], st);
  atomicAdd(&part[cs * 2 + 1], sb);
  __syncthreads();
  if (tid < 20) {
    int cell = row_seg[h] * 20 + tid;
    atomicAdd(&S[cell * 2], part[tid * 2]);
    atomicAdd(&S[cell * 2 + 1], part[tid * 2 + 1]);
  }
}

__global__ __launch_bounds__(1024) void finalize_kernel(
    const int* __restrict__ row_seg, const int* __restrict__ col_seg,
    const float* __restrict__ S, const float* __restrict__ btsum,
    const float* __restrict__ bb, float* __restrict__ tm,
    float* __restrict__ sbm, float* __restrict__ out)
{
  __shared__ int rowcnt[30], colcnt[20];
  const int t = threadIdx.x;
  if (t < 30) rowcnt[t] = 0;
  if (t >= 32 && t < 52) colcnt[t - 32] = 0;
  __syncthreads();
  if (t < 512) atomicAdd(&rowcnt[row_seg[t]], 1);
  else atomicAdd(&colcnt[col_seg[t - 512]], 1);
  __syncthreads();
  if (t < 600) {
    int r = t / 20, c = t - r * 20;
    float cnt = (float)(rowcnt[r] * colcnt[c]);
    float topm = S[2 * t] / (cnt * 144.f) + btsum[0] * (1.f / 36.f);
    float botm = S[2 * t + 1] / (cnt * 4.f) + bb[0];
    tm[t] = topm;
    float s = 1.f / (1.f + expf(-botm));
    sbm[t] = s;
#pragma unroll
    for (int b = 0; b < 4; b++) out[OUTX_SIZE + b * 600 + t] = s;
  }
}

__global__ __launch_bounds__(256) void fill_kernel(
    const int* __restrict__ row_seg, const int* __restrict__ col_seg,
    const float* __restrict__ tm, const float* __restrict__ sbm,
    float* __restrict__ out)
{
  const int idx = blockIdx.x * 256 + threadIdx.x;  // < 1048576
  const int b = idx >> 18;
  const int hw = idx & (NPIX - 1);
  const int h = hw >> 9, w = hw & 511;
  const int cell = row_seg[h] * 20 + col_seg[w];
  const float tmv = tm[cell], sbv = sbm[cell];
  const size_t base = (((size_t)(b * 55)) << 18) + hw;
#pragma unroll
  for (int ch = 0; ch < 36; ch++) out[base + ((size_t)ch << 18)] = tmv;
  out[base + ((size_t)54 << 18)] = sbv;
}

extern "C" void kernel_launch(void* const* d_in, const int* in_sizes, int n_in,
                              void* d_out, int out_size, void* d_ws, size_t ws_size,
                              hipStream_t stream) {
  const float* x       = (const float*)d_in[0];
  const int*   row_seg = (const int*)d_in[1];
  const int*   col_seg = (const int*)d_in[2];
  const float* w1 = (const float*)d_in[3];
  const float* b1 = (const float*)d_in[4];
  const float* w2 = (const float*)d_in[5];
  const float* b2 = (const float*)d_in[6];
  const float* w3 = (const float*)d_in[7];
  const float* b3 = (const float*)d_in[8];
  const float* wt = (const float*)d_in[9];
  const float* bt = (const float*)d_in[10];
  const float* wb = (const float*)d_in[11];
  const float* bb = (const float*)d_in[12];
  float* out = (float*)d_out;
  float* ws  = (float*)d_ws;

  prep_kernel<<<1, 1024, 0, stream>>>(w1, w2, w3, wt, bt, ws);

  dim3 g1(HW / TILE, HW / TILE, NB);
  conv_kernel<<<g1, 256, 0, stream>>>(x, ws + WT_OFF, b1, b2, b3, out);

  dim3 g2(HW / 256, HW);
  cellsum_kernel<<<g2, 256, 0, stream>>>(out, row_seg, col_seg,
                                         ws + WSUM_OFF, wb, ws + S_OFF);

  finalize_kernel<<<1, 1024, 0, stream>>>(row_seg, col_seg, ws + S_OFF,
                                          ws + BTSUM_OFF, bb,
                                          ws + TM_OFF, ws + SBM_OFF, out);

  fill_kernel<<<NB * NPIX / 256, 256, 0, stream>>>(row_seg, col_seg,
                                                   ws + TM_OFF, ws + SBM_OFF, out);
}

// Round 2
// 1201.369 us; speedup vs baseline: 1.4070x; 1.4070x over previous
//
#include <hip/hip_runtime.h>
#include <math.h>

#define HW 512
#define NPIX (HW*HW)            // 262144
#define NB 4
#define NCIN 55
#define OUTX_SIZE (NB*55*NPIX)  // 57671680

// ws layout (float offsets)
#define WT_OFF 0         // 33000 floats: [3][25][55][8]
#define WSUM_OFF 33000   // 18
#define BTSUM_OFF 33018  // 1
#define S_OFF 33024      // 1200: [600][2]
#define TM_OFF 34224     // 600
#define SBM_OFF 34824    // 600

#define TILE 32
#define HALO 6
#define LT 44            // LDS tile dim (rows and cols), stride 44 floats
#define CCH 5

__global__ __launch_bounds__(1024) void prep_kernel(
    const float* __restrict__ w1, const float* __restrict__ w2, const float* __restrict__ w3,
    const float* __restrict__ wt, const float* __restrict__ bt,
    float* __restrict__ ws)
{
  const int t = threadIdx.x;
  for (int e = t; e < 33000; e += 1024) {
    int oc = e & 7;
    int rem = e >> 3;              // (d*25+tap)*55 + cin
    int cin = rem % 55;
    int dt = rem / 55;
    int d = dt / 25, tap = dt - d * 25;
    const float* wsrc = (d == 0) ? w1 : (d == 1) ? w2 : w3;
    ws[WT_OFF + e] = (oc < 6) ? wsrc[(oc * 55 + cin) * 25 + tap] : 0.f;
  }
  if (t < 18) {
    float s = 0.f;
    for (int o = 0; o < 36; o++) s += wt[o * 18 + t];
    ws[WSUM_OFF + t] = s;
  }
  if (t == 18) {
    float s = 0.f;
    for (int o = 0; o < 36; o++) s += bt[o];
    ws[BTSUM_OFF] = s;
  }
  for (int e = t; e < 1200; e += 1024) ws[S_OFF + e] = 0.f;
}

// 32x32 pixel tile, 256 threads, each thread computes 4 w-contiguous pixels.
// Row-stationary inner loop: per (channel, row-offset delta) load one
// 16-float aligned segment (4x ds_read_b128) and do all matching taps from
// registers. LDS stride 44 floats -> uniform b128 bank phases (conflict-free).
__global__ __launch_bounds__(256, 4) void conv_kernel(
    const float* __restrict__ x, const float* __restrict__ wT,
    const float* __restrict__ bias1, const float* __restrict__ bias2,
    const float* __restrict__ bias3, float* __restrict__ out)
{
  __shared__ float xs[CCH * LT * LT];   // 38720 B -> 4 blocks/CU
  const int tid = threadIdx.x;
  const int h0 = blockIdx.y * TILE, w0 = blockIdx.x * TILE;
  const int bz = blockIdx.z;
  const int r = tid >> 3;          // 0..31
  const int cg = (tid & 7) * 4;    // 0,4,..,28

  float acc[18][4];
#pragma unroll
  for (int k = 0; k < 18; k++)
#pragma unroll
    for (int p = 0; p < 4; p++) acc[k][p] = 0.f;

  const bool interior = (h0 >= HALO) && (h0 + TILE + HALO <= HW) &&
                        (w0 >= HALO) && (w0 + TILE + HALO <= HW);

#pragma unroll 1
  for (int c0 = 0; c0 < NCIN; c0 += CCH) {
    __syncthreads();
#pragma unroll 1
    for (int c = 0; c < CCH; c++) {
      const float* xp = x + ((size_t)(bz * NCIN + c0 + c) << 18);
      float* dst = &xs[c * (LT * LT)];
      if (interior) {
        const float* src = xp + (h0 - HALO) * HW + (w0 - HALO);
        for (int e = tid; e < LT * LT; e += 256) {
          int ih = e / LT, iw = e - ih * LT;
          dst[e] = src[ih * HW + iw];
        }
      } else {
        for (int e = tid; e < LT * LT; e += 256) {
          int ih = e / LT, iw = e - ih * LT;
          int gh = h0 - HALO + ih, gw = w0 - HALO + iw;
          float v = 0.f;
          if ((unsigned)gh < (unsigned)HW && (unsigned)gw < (unsigned)HW)
            v = xp[gh * HW + gw];
          dst[e] = v;
        }
      }
    }
    __syncthreads();
#pragma unroll 1
    for (int c = 0; c < CCH; c++) {
      const int cin = c0 + c;
      const float* wp = wT + cin * 8;
      const float* xb = &xs[c * (LT * LT) + (r + HALO) * LT + cg];
#pragma unroll
      for (int di = 0; di < 11; di++) {
        constexpr int DELTA[11] = {-6, -4, -3, -2, -1, 0, 1, 2, 3, 4, 6};
        const int dlt = DELTA[di];
        const float* seg = xb + dlt * LT;
        float se[16];
        float4 q0 = *(const float4*)(seg + 0);
        float4 q1 = *(const float4*)(seg + 4);
        float4 q2 = *(const float4*)(seg + 8);
        float4 q3 = *(const float4*)(seg + 12);
        se[0] = q0.x;  se[1] = q0.y;  se[2] = q0.z;  se[3] = q0.w;
        se[4] = q1.x;  se[5] = q1.y;  se[6] = q1.z;  se[7] = q1.w;
        se[8] = q2.x;  se[9] = q2.y;  se[10] = q2.z; se[11] = q2.w;
        se[12] = q3.x; se[13] = q3.y; se[14] = q3.z; se[15] = q3.w;
#pragma unroll
        for (int d = 0; d < 3; d++) {
          const int dil = d + 1;
          if (dlt % dil == 0 && dlt >= -2 * dil && dlt <= 2 * dil) {
            const int tr = dlt / dil + 2;
#pragma unroll
            for (int tc = 0; tc < 5; tc++) {
              const float* wq = wp + (d * 25 + tr * 5 + tc) * 440;
              const int sb = HALO + (tc - 2) * dil;
#pragma unroll
              for (int oc = 0; oc < 6; oc++) {
                const float wv = wq[oc];
                acc[d * 6 + oc][0] = fmaf(wv, se[sb + 0], acc[d * 6 + oc][0]);
                acc[d * 6 + oc][1] = fmaf(wv, se[sb + 1], acc[d * 6 + oc][1]);
                acc[d * 6 + oc][2] = fmaf(wv, se[sb + 2], acc[d * 6 + oc][2]);
                acc[d * 6 + oc][3] = fmaf(wv, se[sb + 3], acc[d * 6 + oc][3]);
              }
            }
          }
        }
      }
    }
  }

  const int h = h0 + r, w = w0 + cg;
  const size_t pix = (size_t)h * HW + w;
#pragma unroll
  for (int d = 0; d < 3; d++) {
    const float* bp = (d == 0) ? bias1 : (d == 1) ? bias2 : bias3;
#pragma unroll
    for (int oc = 0; oc < 6; oc++) {
      float bv = bp[oc];
      float4 v;
      v.x = fmaxf(acc[d * 6 + oc][0] + bv, 0.f);
      v.y = fmaxf(acc[d * 6 + oc][1] + bv, 0.f);
      v.z = fmaxf(acc[d * 6 + oc][2] + bv, 0.f);
      v.w = fmaxf(acc[d * 6 + oc][3] + bv, 0.f);
      *(float4*)(out + (((size_t)(bz * 55 + 36 + d * 6 + oc)) << 18) + pix) = v;
    }
  }
}

__global__ __launch_bounds__(256) void cellsum_kernel(
    const float* __restrict__ out, const int* __restrict__ row_seg,
    const int* __restrict__ col_seg, const float* __restrict__ wsum,
    const float* __restrict__ wb, float* __restrict__ S)
{
  __shared__ float part[40];
  const int tid = threadIdx.x;
  const int h = blockIdx.y;
  const int w = blockIdx.x * 256 + tid;
  if (tid < 40) part[tid] = 0.f;
  __syncthreads();
  float st = 0.f, sb = 0.f;
  const size_t pix = (size_t)h * HW + w;
#pragma unroll
  for (int b = 0; b < NB; b++)
#pragma unroll
    for (int k = 0; k < 18; k++) {
      float v = out[(((size_t)(b * 55 + 36 + k)) << 18) + pix];
      st = fmaf(wsum[k], v, st);
      sb = fmaf(wb[k], v, sb);
    }
  int cs = col_seg[w];
  atomicAdd(&part[cs * 2], st);
  atomicAdd(&part[cs * 2 + 1], sb);
  __syncthreads();
  if (tid < 20) {
    int cell = row_seg[h] * 20 + tid;
    atomicAdd(&S[cell * 2], part[tid * 2]);
    atomicAdd(&S[cell * 2 + 1], part[tid * 2 + 1]);
  }
}

__global__ __launch_bounds__(1024) void finalize_kernel(
    const int* __restrict__ row_seg, const int* __restrict__ col_seg,
    const float* __restrict__ S, const float* __restrict__ btsum,
    const float* __restrict__ bb, float* __restrict__ tm,
    float* __restrict__ sbm, float* __restrict__ out)
{
  __shared__ int rowcnt[30], colcnt[20];
  const int t = threadIdx.x;
  if (t < 30) rowcnt[t] = 0;
  if (t >= 32 && t < 52) colcnt[t - 32] = 0;
  __syncthreads();
  if (t < 512) atomicAdd(&rowcnt[row_seg[t]], 1);
  else atomicAdd(&colcnt[col_seg[t - 512]], 1);
  __syncthreads();
  if (t < 600) {
    int r = t / 20, c = t - r * 20;
    float cnt = (float)(rowcnt[r] * colcnt[c]);
    float topm = S[2 * t] / (cnt * 144.f) + btsum[0] * (1.f / 36.f);
    float botm = S[2 * t + 1] / (cnt * 4.f) + bb[0];
    tm[t] = topm;
    float s = 1.f / (1.f + expf(-botm));
    sbm[t] = s;
#pragma unroll
    for (int b = 0; b < 4; b++) out[OUTX_SIZE + b * 600 + t] = s;
  }
}

__global__ __launch_bounds__(256) void fill_kernel(
    const int* __restrict__ row_seg, const int* __restrict__ col_seg,
    const float* __restrict__ tm, const float* __restrict__ sbm,
    float* __restrict__ out)
{
  const int idx = blockIdx.x * 256 + threadIdx.x;  // < 1048576
  const int b = idx >> 18;
  const int hw = idx & (NPIX - 1);
  const int h = hw >> 9, w = hw & 511;
  const int cell = row_seg[h] * 20 + col_seg[w];
  const float tmv = tm[cell], sbv = sbm[cell];
  const size_t base = (((size_t)(b * 55)) << 18) + hw;
#pragma unroll
  for (int ch = 0; ch < 36; ch++) out[base + ((size_t)ch << 18)] = tmv;
  out[base + ((size_t)54 << 18)] = sbv;
}

extern "C" void kernel_launch(void* const* d_in, const int* in_sizes, int n_in,
                              void* d_out, int out_size, void* d_ws, size_t ws_size,
                              hipStream_t stream) {
  const float* x       = (const float*)d_in[0];
  const int*   row_seg = (const int*)d_in[1];
  const int*   col_seg = (const int*)d_in[2];
  const float* w1 = (const float*)d_in[3];
  const float* b1 = (const float*)d_in[4];
  const float* w2 = (const float*)d_in[5];
  const float* b2 = (const float*)d_in[6];
  const float* w3 = (const float*)d_in[7];
  const float* b3 = (const float*)d_in[8];
  const float* wt = (const float*)d_in[9];
  const float* bt = (const float*)d_in[10];
  const float* wb = (const float*)d_in[11];
  const float* bb = (const float*)d_in[12];
  float* out = (float*)d_out;
  float* ws  = (float*)d_ws;

  prep_kernel<<<1, 1024, 0, stream>>>(w1, w2, w3, wt, bt, ws);

  dim3 g1(HW / TILE, HW / TILE, NB);
  conv_kernel<<<g1, 256, 0, stream>>>(x, ws + WT_OFF, b1, b2, b3, out);

  dim3 g2(HW / 256, HW);
  cellsum_kernel<<<g2, 256, 0, stream>>>(out, row_seg, col_seg,
                                         ws + WSUM_OFF, wb, ws + S_OFF);

  finalize_kernel<<<1, 1024, 0, stream>>>(row_seg, col_seg, ws + S_OFF,
                                          ws + BTSUM_OFF, bb,
                                          ws + TM_OFF, ws + SBM_OFF, out);

  fill_kernel<<<NB * NPIX / 256, 256, 0, stream>>>(row_seg, col_seg,
                                                   ws + TM_OFF, ws + SBM_OFF, out);
}

// Round 3
// 906.747 us; speedup vs baseline: 1.8642x; 1.3249x over previous
//
#include <hip/hip_runtime.h>
#include <math.h>

#define HW 512
#define NPIX (HW*HW)            // 262144
#define NB 4
#define NCIN 55
#define NPAIR 28                // 55 channels -> 28 f16x2 pairs (last half-zero)
#define OUTX_SIZE (NB*55*NPIX)  // 57671680

// ws layout (float/uint offsets)
#define WP_OFF 0         // 16800 uints: [28 pairs][75 taps][8 oc] f16x2
#define WSUM_OFF 16800   // 18
#define BTSUM_OFF 16818  // 1
#define S_OFF 16832      // 1200: [600][2]
#define TM_OFF 18032     // 600
#define SBM_OFF 18632    // 600

#define TILE 32
#define HALO 6
#define LT 44            // staged tile dim; stride 44 dwords (1 dword = 2ch f16)
#define CP 4             // channel-pairs staged per iteration

typedef _Float16 half2v __attribute__((ext_vector_type(2)));

__device__ __forceinline__ uint pack_f16x2(float a, float b) {
  return __builtin_bit_cast(uint, __builtin_amdgcn_cvt_pkrtz(a, b));
}

__device__ __forceinline__ float dot2u(uint a, uint b, float c) {
#if defined(__has_builtin) && __has_builtin(__builtin_amdgcn_fdot2)
  return __builtin_amdgcn_fdot2(__builtin_bit_cast(half2v, a),
                                __builtin_bit_cast(half2v, b), c, false);
#else
  half2v av = __builtin_bit_cast(half2v, a), bv = __builtin_bit_cast(half2v, b);
  return fmaf((float)av.x, (float)bv.x, fmaf((float)av.y, (float)bv.y, c));
#endif
}

__global__ __launch_bounds__(1024) void prep_kernel(
    const float* __restrict__ w1, const float* __restrict__ w2, const float* __restrict__ w3,
    const float* __restrict__ wt, const float* __restrict__ bt,
    float* __restrict__ ws)
{
  const int t = threadIdx.x;
  uint* wp = (uint*)(ws + WP_OFF);
  for (int e = t; e < NPAIR * 75 * 8; e += 1024) {
    int oc = e & 7;
    int rem = e >> 3;            // pair*75 + dt
    int dt = rem % 75;
    int pair = rem / 75;
    int d = dt / 25, tap = dt - d * 25;
    const float* wsrc = (d == 0) ? w1 : (d == 1) ? w2 : w3;
    int c0 = 2 * pair;
    float lo = 0.f, hi = 0.f;
    if (oc < 6) {
      lo = wsrc[(oc * 55 + c0) * 25 + tap];
      if (c0 + 1 < NCIN) hi = wsrc[(oc * 55 + c0 + 1) * 25 + tap];
    }
    wp[e] = pack_f16x2(lo, hi);
  }
  if (t < 18) {
    float s = 0.f;
    for (int o = 0; o < 36; o++) s += wt[o * 18 + t];
    ws[WSUM_OFF + t] = s;
  }
  if (t == 18) {
    float s = 0.f;
    for (int o = 0; o < 36; o++) s += bt[o];
    ws[BTSUM_OFF] = s;
  }
  for (int e = t; e < 1200; e += 1024) ws[S_OFF + e] = 0.f;
}

// 32x32 px tile, 256 threads, 4 w-contiguous px/thread. Channels processed as
// f16x2 pairs staged channel-interleaved in LDS; inner op = v_dot2_f32_f16
// (2 MACs/lane/instr, fp32 accumulate). All LDS reads are 16B-aligned b128.
__global__ __launch_bounds__(256) void conv_kernel(
    const float* __restrict__ x, const uint* __restrict__ wP,
    const float* __restrict__ bias1, const float* __restrict__ bias2,
    const float* __restrict__ bias3, float* __restrict__ out)
{
  __shared__ uint xs[CP * LT * LT];   // 30976 B
  const int tid = threadIdx.x;
  const int h0 = blockIdx.y * TILE, w0 = blockIdx.x * TILE;
  const int bz = blockIdx.z;
  const int r = tid >> 3;          // 0..31
  const int cg = (tid & 7) * 4;    // 0,4,..,28

  float acc[18][4];
#pragma unroll
  for (int k = 0; k < 18; k++)
#pragma unroll
    for (int p = 0; p < 4; p++) acc[k][p] = 0.f;

  const bool interior = (h0 >= HALO) && (h0 + TILE + HALO <= HW) &&
                        (w0 >= HALO) && (w0 + TILE + HALO <= HW);

#pragma unroll 1
  for (int cp0 = 0; cp0 < NPAIR; cp0 += CP) {
    __syncthreads();
#pragma unroll 1
    for (int p = 0; p < CP; p++) {
      const int pair = cp0 + p;
      const float* xA = x + ((size_t)(bz * NCIN + 2 * pair) << 18);
      const float* xB = xA + ((size_t)1 << 18);
      const bool hasB = (2 * pair + 1) < NCIN;
      uint* dst = &xs[p * (LT * LT)];
      if (interior) {
        const float* sA = xA + (h0 - HALO) * HW + (w0 - HALO);
        const float* sB = xB + (h0 - HALO) * HW + (w0 - HALO);
        for (int e = tid; e < LT * LT; e += 256) {
          int ih = e / LT, iw = e - ih * LT;
          float a = sA[ih * HW + iw];
          float b = hasB ? sB[ih * HW + iw] : 0.f;
          dst[e] = pack_f16x2(a, b);
        }
      } else {
        for (int e = tid; e < LT * LT; e += 256) {
          int ih = e / LT, iw = e - ih * LT;
          int gh = h0 - HALO + ih, gw = w0 - HALO + iw;
          float a = 0.f, b = 0.f;
          if ((unsigned)gh < (unsigned)HW && (unsigned)gw < (unsigned)HW) {
            a = xA[gh * HW + gw];
            if (hasB) b = xB[gh * HW + gw];
          }
          dst[e] = pack_f16x2(a, b);
        }
      }
    }
    __syncthreads();
#pragma unroll 1
    for (int p = 0; p < CP; p++) {
      const int pair = cp0 + p;
      const uint* wp = wP + pair * 600;             // [75][8] f16x2
      const uint* xb = &xs[p * (LT * LT) + (r + HALO) * LT + cg];
#pragma unroll
      for (int di = 0; di < 11; di++) {
        constexpr int DELTA[11] = {-6, -4, -3, -2, -1, 0, 1, 2, 3, 4, 6};
        const int dlt = DELTA[di];
        const uint* seg = xb + dlt * LT;
        uint4 u0 = *(const uint4*)(seg + 0);
        uint4 u1 = *(const uint4*)(seg + 4);
        uint4 u2 = *(const uint4*)(seg + 8);
        uint4 u3 = *(const uint4*)(seg + 12);
        uint se[16];
        se[0] = u0.x;  se[1] = u0.y;  se[2] = u0.z;  se[3] = u0.w;
        se[4] = u1.x;  se[5] = u1.y;  se[6] = u1.z;  se[7] = u1.w;
        se[8] = u2.x;  se[9] = u2.y;  se[10] = u2.z; se[11] = u2.w;
        se[12] = u3.x; se[13] = u3.y; se[14] = u3.z; se[15] = u3.w;
#pragma unroll
        for (int d = 0; d < 3; d++) {
          const int dil = d + 1;
          if (dlt % dil == 0 && dlt >= -2 * dil && dlt <= 2 * dil) {
            const int tr = dlt / dil + 2;
#pragma unroll
            for (int tc = 0; tc < 5; tc++) {
              const uint* wq = wp + (d * 25 + tr * 5 + tc) * 8;
              const int sb = HALO + (tc - 2) * dil;
#pragma unroll
              for (int oc = 0; oc < 6; oc++) {
                const uint wv = wq[oc];
                acc[d * 6 + oc][0] = dot2u(se[sb + 0], wv, acc[d * 6 + oc][0]);
                acc[d * 6 + oc][1] = dot2u(se[sb + 1], wv, acc[d * 6 + oc][1]);
                acc[d * 6 + oc][2] = dot2u(se[sb + 2], wv, acc[d * 6 + oc][2]);
                acc[d * 6 + oc][3] = dot2u(se[sb + 3], wv, acc[d * 6 + oc][3]);
              }
            }
          }
        }
      }
    }
  }

  const int h = h0 + r, w = w0 + cg;
  const size_t pix = (size_t)h * HW + w;
#pragma unroll
  for (int d = 0; d < 3; d++) {
    const float* bp = (d == 0) ? bias1 : (d == 1) ? bias2 : bias3;
#pragma unroll
    for (int oc = 0; oc < 6; oc++) {
      float bv = bp[oc];
      float4 v;
      v.x = fmaxf(acc[d * 6 + oc][0] + bv, 0.f);
      v.y = fmaxf(acc[d * 6 + oc][1] + bv, 0.f);
      v.z = fmaxf(acc[d * 6 + oc][2] + bv, 0.f);
      v.w = fmaxf(acc[d * 6 + oc][3] + bv, 0.f);
      *(float4*)(out + (((size_t)(bz * 55 + 36 + d * 6 + oc)) << 18) + pix) = v;
    }
  }
}

__global__ __launch_bounds__(256) void cellsum_kernel(
    const float* __restrict__ out, const int* __restrict__ row_seg,
    const int* __restrict__ col_seg, const float* __restrict__ wsum,
    const float* __restrict__ wb, float* __restrict__ S)
{
  __shared__ float part[40];
  const int tid = threadIdx.x;
  const int h = blockIdx.y;
  const int w = blockIdx.x * 256 + tid;
  if (tid < 40) part[tid] = 0.f;
  __syncthreads();
  float st = 0.f, sb = 0.f;
  const size_t pix = (size_t)h * HW + w;
#pragma unroll
  for (int b = 0; b < NB; b++)
#pragma unroll
    for (int k = 0; k < 18; k++) {
      float v = out[(((size_t)(b * 55 + 36 + k)) << 18) + pix];
      st = fmaf(wsum[k], v, st);
      sb = fmaf(wb[k], v, sb);
    }
  int cs = col_seg[w];
  atomicAdd(&part[cs * 2], st);
  atomicAdd(&part[cs * 2 + 1], sb);
  __syncthreads();
  if (tid < 20) {
    int cell = row_seg[h] * 20 + tid;
    atomicAdd(&S[cell * 2], part[tid * 2]);
    atomicAdd(&S[cell * 2 + 1], part[tid * 2 + 1]);
  }
}

__global__ __launch_bounds__(1024) void finalize_kernel(
    const int* __restrict__ row_seg, const int* __restrict__ col_seg,
    const float* __restrict__ S, const float* __restrict__ btsum,
    const float* __restrict__ bb, float* __restrict__ tm,
    float* __restrict__ sbm, float* __restrict__ out)
{
  __shared__ int rowcnt[30], colcnt[20];
  const int t = threadIdx.x;
  if (t < 30) rowcnt[t] = 0;
  if (t >= 32 && t < 52) colcnt[t - 32] = 0;
  __syncthreads();
  if (t < 512) atomicAdd(&rowcnt[row_seg[t]], 1);
  else atomicAdd(&colcnt[col_seg[t - 512]], 1);
  __syncthreads();
  if (t < 600) {
    int r = t / 20, c = t - r * 20;
    float cnt = (float)(rowcnt[r] * colcnt[c]);
    float topm = S[2 * t] / (cnt * 144.f) + btsum[0] * (1.f / 36.f);
    float botm = S[2 * t + 1] / (cnt * 4.f) + bb[0];
    tm[t] = topm;
    float s = 1.f / (1.f + expf(-botm));
    sbm[t] = s;
#pragma unroll
    for (int b = 0; b < 4; b++) out[OUTX_SIZE + b * 600 + t] = s;
  }
}

__global__ __launch_bounds__(256) void fill_kernel(
    const int* __restrict__ row_seg, const int* __restrict__ col_seg,
    const float* __restrict__ tm, const float* __restrict__ sbm,
    float* __restrict__ out)
{
  const int idx = blockIdx.x * 256 + threadIdx.x;  // < 1048576
  const int b = idx >> 18;
  const int hw = idx & (NPIX - 1);
  const int h = hw >> 9, w = hw & 511;
  const int cell = row_seg[h] * 20 + col_seg[w];
  const float tmv = tm[cell], sbv = sbm[cell];
  const size_t base = (((size_t)(b * 55)) << 18) + hw;
#pragma unroll
  for (int ch = 0; ch < 36; ch++) out[base + ((size_t)ch << 18)] = tmv;
  out[base + ((size_t)54 << 18)] = sbv;
}

extern "C" void kernel_launch(void* const* d_in, const int* in_sizes, int n_in,
                              void* d_out, int out_size, void* d_ws, size_t ws_size,
                              hipStream_t stream) {
  const float* x       = (const float*)d_in[0];
  const int*   row_seg = (const int*)d_in[1];
  const int*   col_seg = (const int*)d_in[2];
  const float* w1 = (const float*)d_in[3];
  const float* b1 = (const float*)d_in[4];
  const float* w2 = (const float*)d_in[5];
  const float* b2 = (const float*)d_in[6];
  const float* w3 = (const float*)d_in[7];
  const float* b3 = (const float*)d_in[8];
  const float* wt = (const float*)d_in[9];
  const float* bt = (const float*)d_in[10];
  const float* wb = (const float*)d_in[11];
  const float* bb = (const float*)d_in[12];
  float* out = (float*)d_out;
  float* ws  = (float*)d_ws;

  prep_kernel<<<1, 1024, 0, stream>>>(w1, w2, w3, wt, bt, ws);

  dim3 g1(HW / TILE, HW / TILE, NB);
  conv_kernel<<<g1, 256, 0, stream>>>(x, (const uint*)(ws + WP_OFF),
                                      b1, b2, b3, out);

  dim3 g2(HW / 256, HW);
  cellsum_kernel<<<g2, 256, 0, stream>>>(out, row_seg, col_seg,
                                         ws + WSUM_OFF, wb, ws + S_OFF);

  finalize_kernel<<<1, 1024, 0, stream>>>(row_seg, col_seg, ws + S_OFF,
                                          ws + BTSUM_OFF, bb,
                                          ws + TM_OFF, ws + SBM_OFF, out);

  fill_kernel<<<NB * NPIX / 256, 256, 0, stream>>>(row_seg, col_seg,
                                                   ws + TM_OFF, ws + SBM_OFF, out);
}